// Round 1
// baseline (5657.356 us; speedup 1.0000x reference)
//
#include <hip/hip_runtime.h>
#include <math.h>

#define B_ 8
#define N_ 16384
#define D_ 384
#define H_ 8
#define C_ 48
#define TD_ 1152
#define M_ (B_*N_)
#define CTX_ELEMS (B_*H_*C_*C_)   /* 147456 */
#define Z_ELEMS   (B_*H_*C_)      /* 3072   */

// ---------------------------------------------------------------------------
// Kernel A: per 256-token block — compute k,v tiles (x @ W_kv), exp(k),
// accumulate unnormalized context[b,h,c,d] += e^{k}·v and Z[b,h,c] += e^{k}
// via register accumulation across 4×64-token tiles, then atomics.
// grid = 512 blocks (64 per batch), block = 256.
// ---------------------------------------------------------------------------
__global__ __launch_bounds__(256) void kA_ctx(
    const float* __restrict__ x, const float* __restrict__ Wqkv,
    float* __restrict__ ctx, float* __restrict__ Zg)
{
    __shared__ __align__(16) float xs[D_ * 68];   // transposed [dd][t], pad 68
    __shared__ __align__(16) float kv[96 * 68];   // transposed [c96][t]; rows 0..47 = e^k, 48..95 = v

    const int tid = threadIdx.x;
    const int bid = blockIdx.x;
    const int b   = bid >> 6;

    // GEMM mapping: 64 tokens x 96 channels -> thread = 4 tokens x 6 channels
    const int tt = tid & 15;     // token group (tokens tt*4 .. tt*4+3)
    const int cc = tid >> 4;     // channel group (c96 = cc*6 .. cc*6+5); cc<8 -> k, cc>=8 -> v
    // ctx mapping: 48x48 -> thread = 3 c x 3 d
    const int ci = tid >> 4;     // c = ci*3 + a
    const int di = tid & 15;     // d = di*3 + e

    float ctx_acc[8][3][3];
    float z_acc[8][3];
#pragma unroll
    for (int h = 0; h < 8; ++h) {
#pragma unroll
        for (int a = 0; a < 3; ++a) {
            z_acc[h][a] = 0.f;
#pragma unroll
            for (int e = 0; e < 3; ++e) ctx_acc[h][a][e] = 0.f;
        }
    }

    const int st = tid & 63;     // staging token
    const int sw = tid >> 6;     // staging wave

    for (int tile = 0; tile < 4; ++tile) {
        const int tok0 = bid * 256 + tile * 64;   // global token index
        __syncthreads();
        {
            const float* xg = x + (size_t)(tok0 + st) * D_;
#pragma unroll
            for (int i = 0; i < 24; ++i) {
                const int dd = (i * 4 + sw) * 4;
                const float4 v = *(const float4*)(xg + dd);
                xs[(dd + 0) * 68 + st] = v.x;
                xs[(dd + 1) * 68 + st] = v.y;
                xs[(dd + 2) * 68 + st] = v.z;
                xs[(dd + 3) * 68 + st] = v.w;
            }
        }
        __syncthreads();

#pragma unroll
        for (int h = 0; h < 8; ++h) {
            const int c0 = cc * 6;
            const float* wcol = (cc < 8)
                ? (Wqkv + 384 + h * 48 + c0)           // k columns
                : (Wqkv + 768 + h * 48 + (c0 - 48));   // v columns
            float acc[4][6];
#pragma unroll
            for (int i = 0; i < 4; ++i)
#pragma unroll
                for (int j = 0; j < 6; ++j) acc[i][j] = 0.f;

#pragma unroll 4
            for (int dd = 0; dd < D_; ++dd) {
                const float4 xv = *(const float4*)&xs[dd * 68 + tt * 4];
                const float* wr = wcol + (size_t)dd * TD_;
                const float2 wa = *(const float2*)(wr + 0);
                const float2 wb = *(const float2*)(wr + 2);
                const float2 wc = *(const float2*)(wr + 4);
                const float w[6]   = { wa.x, wa.y, wb.x, wb.y, wc.x, wc.y };
                const float xv4[4] = { xv.x, xv.y, xv.z, xv.w };
#pragma unroll
                for (int i = 0; i < 4; ++i)
#pragma unroll
                    for (int j = 0; j < 6; ++j)
                        acc[i][j] = fmaf(xv4[i], w[j], acc[i][j]);
            }

            __syncthreads();   // previous kv readers done
#pragma unroll
            for (int j = 0; j < 6; ++j) {
                float4 o;
                o.x = acc[0][j]; o.y = acc[1][j]; o.z = acc[2][j]; o.w = acc[3][j];
                if (cc < 8) { o.x = __expf(o.x); o.y = __expf(o.y); o.z = __expf(o.z); o.w = __expf(o.w); }
                *(float4*)&kv[(c0 + j) * 68 + tt * 4] = o;
            }
            __syncthreads();

            // context accumulation: ctx[c][d] += sum_t ek[t][c] * v[t][d]
            const int ca = ci * 3, da = 48 + di * 3;
#pragma unroll 4
            for (int t4 = 0; t4 < 16; ++t4) {
                float4 vv[3];
#pragma unroll
                for (int d = 0; d < 3; ++d)
                    vv[d] = *(const float4*)&kv[(da + d) * 68 + t4 * 4];
#pragma unroll
                for (int a = 0; a < 3; ++a) {
                    const float4 ev = *(const float4*)&kv[(ca + a) * 68 + t4 * 4];
                    z_acc[h][a] += (ev.x + ev.y) + (ev.z + ev.w);
#pragma unroll
                    for (int d = 0; d < 3; ++d) {
                        ctx_acc[h][a][d] = fmaf(ev.x, vv[d].x,
                                           fmaf(ev.y, vv[d].y,
                                           fmaf(ev.z, vv[d].z,
                                           fmaf(ev.w, vv[d].w, ctx_acc[h][a][d]))));
                    }
                }
            }
        }
    }

#pragma unroll
    for (int h = 0; h < 8; ++h) {
#pragma unroll
        for (int a = 0; a < 3; ++a) {
#pragma unroll
            for (int e = 0; e < 3; ++e)
                atomicAdd(&ctx[((size_t)(b * 8 + h) * 48 + (ci * 3 + a)) * 48 + (di * 3 + e)],
                          ctx_acc[h][a][e]);
            if (di == 0)
                atomicAdd(&Zg[(b * 8 + h) * 48 + (ci * 3 + a)], z_acc[h][a]);
        }
    }
}

// ---------------------------------------------------------------------------
// Kernel B: normalize context rows by Z (k-softmax denominator). In-place.
// ---------------------------------------------------------------------------
__global__ void kB_norm(float* __restrict__ ctx, const float* __restrict__ Zg)
{
    const int e = blockIdx.x * 256 + threadIdx.x;
    if (e < CTX_ELEMS) ctx[e] = ctx[e] / Zg[e / 48];
}

// ---------------------------------------------------------------------------
// Kernel C: per 32-token tile — q logits (x @ W_q), softmax over C,
// y = q̂ @ ctx, out = y @ W_proj + b. Head-pair loop, fully fused.
// grid = 4096 blocks (512 per batch), block = 256.
// ---------------------------------------------------------------------------
__global__ __launch_bounds__(256) void kC_out(
    const float* __restrict__ x, const float* __restrict__ Wqkv,
    const float* __restrict__ ctx, const float* __restrict__ Wp,
    const float* __restrict__ bp, float* __restrict__ out)
{
    __shared__ __align__(16) float xs[D_ * 34];   // transposed [dd][t], pad 34
    __shared__ __align__(16) float qb[96 * 34];   // q logits -> q̂, [c96][t]
    __shared__ __align__(16) float yb[96 * 34];   // y, [c96][t]

    const int tid = threadIdx.x;
    const int bid = blockIdx.x;
    const int tok0 = bid * 32;
    const int b = bid >> 9;      // 512 blocks per batch

    {
        const int st = tid & 31, sw = tid >> 5;
        const float* xg = x + (size_t)(tok0 + st) * D_;
#pragma unroll
        for (int i = 0; i < 12; ++i) {
            const int dd = (i * 8 + sw) * 4;
            const float4 v = *(const float4*)(xg + dd);
            xs[(dd + 0) * 34 + st] = v.x;
            xs[(dd + 1) * 34 + st] = v.y;
            xs[(dd + 2) * 34 + st] = v.z;
            xs[(dd + 3) * 34 + st] = v.w;
        }
    }
    __syncthreads();

    const int tt = tid & 15;     // tokens tt*2, tt*2+1
    const int cg = tid >> 4;     // channel group (6 ch) / output col group (24 cols)

    float acc_out[2][24];
#pragma unroll
    for (int i = 0; i < 2; ++i)
#pragma unroll
        for (int j = 0; j < 24; ++j) acc_out[i][j] = 0.f;

    for (int hp = 0; hp < 4; ++hp) {
        // ---- q-GEMM: 32 tokens x 96 cols (heads 2hp, 2hp+1) ----
        float a2[2][6];
#pragma unroll
        for (int i = 0; i < 2; ++i)
#pragma unroll
            for (int j = 0; j < 6; ++j) a2[i][j] = 0.f;
        const float* wq = Wqkv + hp * 96 + cg * 6;
#pragma unroll 4
        for (int dd = 0; dd < D_; ++dd) {
            const float2 xv = *(const float2*)&xs[dd * 34 + tt * 2];
            const float* wr = wq + (size_t)dd * TD_;
            const float2 wa = *(const float2*)(wr + 0);
            const float2 wb = *(const float2*)(wr + 2);
            const float2 wc = *(const float2*)(wr + 4);
            const float w[6] = { wa.x, wa.y, wb.x, wb.y, wc.x, wc.y };
#pragma unroll
            for (int j = 0; j < 6; ++j) {
                a2[0][j] = fmaf(xv.x, w[j], a2[0][j]);
                a2[1][j] = fmaf(xv.y, w[j], a2[1][j]);
            }
        }
        __syncthreads();   // S1: previous hp's qb/yb readers done
#pragma unroll
        for (int j = 0; j < 6; ++j) {
            float2 o; o.x = a2[0][j]; o.y = a2[1][j];
            *(float2*)&qb[(cg * 6 + j) * 34 + tt * 2] = o;
        }
        __syncthreads();   // S2

        // ---- softmax over C=48 per (token, head): 64 tasks on first wave ----
        if (tid < 64) {
            const int t = tid & 31, hh = tid >> 5;
            const int base = hh * 48;
            float m = -1e30f;
            for (int c = 0; c < 48; ++c) m = fmaxf(m, qb[(base + c) * 34 + t]);
            float s = 0.f;
            for (int c = 0; c < 48; ++c) {
                const float e = __expf(qb[(base + c) * 34 + t] - m);
                qb[(base + c) * 34 + t] = e;
                s += e;
            }
            const float inv = 1.f / s;
            for (int c = 0; c < 48; ++c) qb[(base + c) * 34 + t] *= inv;
        }
        __syncthreads();   // S3

        // ---- y = q̂ @ ctx (per head 48x48) ----
        const int hl = cg >> 3;
        const int h  = hp * 2 + hl;
        const int d0 = (cg & 7) * 6;
        const float* cx = ctx + (size_t)(b * 8 + h) * 48 * 48 + d0;
        float y2[2][6];
#pragma unroll
        for (int i = 0; i < 2; ++i)
#pragma unroll
            for (int j = 0; j < 6; ++j) y2[i][j] = 0.f;
#pragma unroll 4
        for (int c = 0; c < 48; ++c) {
            const float2 q2 = *(const float2*)&qb[(hl * 48 + c) * 34 + tt * 2];
            const float2 ca_ = *(const float2*)(cx + c * 48 + 0);
            const float2 cb_ = *(const float2*)(cx + c * 48 + 2);
            const float2 cd_ = *(const float2*)(cx + c * 48 + 4);
            const float cv[6] = { ca_.x, ca_.y, cb_.x, cb_.y, cd_.x, cd_.y };
#pragma unroll
            for (int j = 0; j < 6; ++j) {
                y2[0][j] = fmaf(q2.x, cv[j], y2[0][j]);
                y2[1][j] = fmaf(q2.y, cv[j], y2[1][j]);
            }
        }
#pragma unroll
        for (int j = 0; j < 6; ++j) {
            float2 o; o.x = y2[0][j]; o.y = y2[1][j];
            *(float2*)&yb[(cg * 6 + j) * 34 + tt * 2] = o;
        }
        __syncthreads();   // S4

        // ---- proj partial: acc_out += y[:, hp*96 + k] * Wp[hp*96 + k, :] ----
        const float* wp = Wp + (size_t)(hp * 96) * D_ + cg * 24;
#pragma unroll 2
        for (int k = 0; k < 96; ++k) {
            const float2 yv = *(const float2*)&yb[k * 34 + tt * 2];
            const float* wr = wp + (size_t)k * D_;
#pragma unroll
            for (int j4 = 0; j4 < 6; ++j4) {
                const float4 w = *(const float4*)(wr + j4 * 4);
                const float wv[4] = { w.x, w.y, w.z, w.w };
#pragma unroll
                for (int l = 0; l < 4; ++l) {
                    acc_out[0][j4 * 4 + l] = fmaf(yv.x, wv[l], acc_out[0][j4 * 4 + l]);
                    acc_out[1][j4 * 4 + l] = fmaf(yv.y, wv[l], acc_out[1][j4 * 4 + l]);
                }
            }
        }
        // next iteration's S1 protects yb/qb
    }

    // ---- epilogue: bias + store ----
#pragma unroll
    for (int i = 0; i < 2; ++i) {
        const int trow = tok0 + tt * 2 + i;
        float* og = out + (size_t)trow * D_ + cg * 24;
#pragma unroll
        for (int j4 = 0; j4 < 6; ++j4) {
            float4 o;
            o.x = acc_out[i][j4 * 4 + 0] + bp[cg * 24 + j4 * 4 + 0];
            o.y = acc_out[i][j4 * 4 + 1] + bp[cg * 24 + j4 * 4 + 1];
            o.z = acc_out[i][j4 * 4 + 2] + bp[cg * 24 + j4 * 4 + 2];
            o.w = acc_out[i][j4 * 4 + 3] + bp[cg * 24 + j4 * 4 + 3];
            *(float4*)(og + j4 * 4) = o;
        }
    }
}

// ---------------------------------------------------------------------------
extern "C" void kernel_launch(void* const* d_in, const int* in_sizes, int n_in,
                              void* d_out, int out_size, void* d_ws, size_t ws_size,
                              hipStream_t stream)
{
    (void)in_sizes; (void)n_in; (void)out_size; (void)ws_size;
    const float* x    = (const float*)d_in[0];
    const float* Wqkv = (const float*)d_in[1];
    const float* Wp   = (const float*)d_in[2];
    const float* bp   = (const float*)d_in[3];
    float* out = (float*)d_out;

    float* ctx = (float*)d_ws;            // 147456 floats
    float* Zg  = ctx + CTX_ELEMS;         // 3072 floats

    hipMemsetAsync(d_ws, 0, (CTX_ELEMS + Z_ELEMS) * sizeof(float), stream);
    kA_ctx<<<dim3(512), dim3(256), 0, stream>>>(x, Wqkv, ctx, Zg);
    kB_norm<<<dim3((CTX_ELEMS + 255) / 256), dim3(256), 0, stream>>>(ctx, Zg);
    kC_out<<<dim3(M_ / 32), dim3(256), 0, stream>>>(x, Wqkv, ctx, Wp, bp, out);
}

// Round 2
// 824.763 us; speedup vs baseline: 6.8594x; 6.8594x over previous
//
#include <hip/hip_runtime.h>
#include <math.h>

#define B_ 8
#define N_ 16384
#define D_ 384
#define TD_ 1152
#define M_ (B_*N_)
#define CTX_ELEMS (B_*8*48*48)    /* 147456 fp32 */
#define Z_ELEMS   (B_*8*48)       /* 3072 fp32   */

typedef __attribute__((ext_vector_type(8))) short short8;
typedef __attribute__((ext_vector_type(4))) float f32x4;
typedef __attribute__((ext_vector_type(4))) unsigned short us4;
typedef __attribute__((ext_vector_type(8))) unsigned short us8;

__device__ __forceinline__ unsigned short f2bf(float f){
    union { float f; unsigned u; } v; v.f = f;
    unsigned r = v.u + 0x7FFFu + ((v.u >> 16) & 1u);   // RNE
    return (unsigned short)(r >> 16);
}

#define MFMA(a,b,c) __builtin_amdgcn_mfma_f32_16x16x32_bf16((a),(b),(c),0,0,0)

// ---------------------------------------------------------------------------
// kP: transpose + bf16-ify weights. WqkvT[col][d] (1152x384), WpT[col][d] (384x384)
// ---------------------------------------------------------------------------
__global__ void kP(const float* __restrict__ Wqkv, const float* __restrict__ Wp,
                   unsigned short* __restrict__ WqkvT, unsigned short* __restrict__ WpT)
{
    __shared__ float t[32][33];
    int bi = blockIdx.x;
    const float* src; unsigned short* dst; int ldS, c0, d0;
    if (bi < 432) { src = Wqkv; dst = WqkvT; ldS = 1152; c0 = (bi % 36) * 32; d0 = (bi / 36) * 32; }
    else { bi -= 432; src = Wp; dst = WpT; ldS = 384; c0 = (bi % 12) * 32; d0 = (bi / 12) * 32; }
    const int cx = threadIdx.x & 31, ry = threadIdx.x >> 5;
#pragma unroll
    for (int k = 0; k < 4; ++k) {
        int r = ry + k * 8;
        t[r][cx] = src[(size_t)(d0 + r) * ldS + c0 + cx];
    }
    __syncthreads();
#pragma unroll
    for (int k = 0; k < 4; ++k) {
        int r = ry + k * 8;
        dst[(size_t)(c0 + r) * 384 + d0 + cx] = f2bf(t[cx][r]);
    }
}

// ---------------------------------------------------------------------------
// kA: per block (512 thr = 8 waves, wave = head): 8 token-tiles of 64.
// MFMA k,v GEMM -> exp(k) -> swizzled LDS -> MFMA ctx accumulation -> atomics.
// grid = 256 (32 blocks per batch x 8 tiles each).
// ---------------------------------------------------------------------------
__global__ __launch_bounds__(512, 2) void kA(const float* __restrict__ x,
        const unsigned short* __restrict__ WqkvT,
        float* __restrict__ ctx, float* __restrict__ Z)
{
    __shared__ __align__(16) unsigned short xs[64 * 392];    // x tile, [t][d], bf16
    __shared__ __align__(16) unsigned short kv[8 * 96 * 64]; // per-wave [row96][t64], XOR-swizzled

    const int tid = threadIdx.x;
    const int w   = tid >> 6;       // wave = head
    const int l   = tid & 63;
    const int q   = l >> 4;
    const int c16 = l & 15;
    const int blk = blockIdx.x;
    const int b   = blk >> 5;
    const int tbase = (blk & 31) * 8;
    unsigned short* kvw = kv + w * (96 * 64);

    f32x4 ctxacc[3][3];
    float zp[3] = {0.f, 0.f, 0.f};
#pragma unroll
    for (int i = 0; i < 3; ++i)
#pragma unroll
        for (int j = 0; j < 3; ++j) ctxacc[i][j] = (f32x4){0.f, 0.f, 0.f, 0.f};

    const int st = tid >> 3, sq = tid & 7;

    for (int g = 0; g < 8; ++g) {
        const size_t tok0 = (size_t)b * 16384 + (size_t)(tbase + g) * 64;
        __syncthreads();
        {   // stage x -> bf16 LDS (coalesced 128B per 8-lane group)
            const float* xg = x + (tok0 + st) * 384 + sq * 4;
            unsigned short* xw = xs + st * 392 + sq * 4;
#pragma unroll
            for (int i = 0; i < 12; ++i) {
                float4 v = *(const float4*)(xg + i * 32);
                us4 o; o.x = f2bf(v.x); o.y = f2bf(v.y); o.z = f2bf(v.z); o.w = f2bf(v.w);
                *(us4*)(xw + i * 32) = o;
            }
        }
        __syncthreads();

        // --- k,v GEMM: 64 tok x 96 cols (this head's k:48 + v:48), K=384 ---
        f32x4 kva[4][6];
#pragma unroll
        for (int mt = 0; mt < 4; ++mt)
#pragma unroll
            for (int j = 0; j < 6; ++j) kva[mt][j] = (f32x4){0.f, 0.f, 0.f, 0.f};

#pragma unroll
        for (int ks = 0; ks < 12; ++ks) {
            short8 a[4];
#pragma unroll
            for (int mt = 0; mt < 4; ++mt)
                a[mt] = *(const short8*)(xs + (mt * 16 + c16) * 392 + ks * 32 + q * 8);
#pragma unroll
            for (int j = 0; j < 6; ++j) {
                const int colrow = (j < 3) ? (384 + w * 48 + j * 16 + c16)
                                           : (768 + w * 48 + (j - 3) * 16 + c16);
                short8 bf = *(const short8*)(WqkvT + (size_t)colrow * 384 + ks * 32 + q * 8);
#pragma unroll
                for (int mt = 0; mt < 4; ++mt)
                    kva[mt][j] = MFMA(a[mt], bf, kva[mt][j]);
            }
        }

        // --- exp(k), pack bf16, write swizzled [row][t] ---
#pragma unroll
        for (int mt = 0; mt < 4; ++mt) {
            const int chunk = 2 * mt + (q >> 1);
            const int tin = (q & 1) * 4;
#pragma unroll
            for (int j = 0; j < 6; ++j) {
                f32x4 vv = kva[mt][j];
                us4 o;
                int row;
                if (j < 3) {
                    row = j * 16 + c16;
                    float e0 = __expf(vv.x), e1 = __expf(vv.y), e2 = __expf(vv.z), e3 = __expf(vv.w);
                    zp[j] += (e0 + e1) + (e2 + e3);
                    o.x = f2bf(e0); o.y = f2bf(e1); o.z = f2bf(e2); o.w = f2bf(e3);
                } else {
                    row = 48 + (j - 3) * 16 + c16;
                    o.x = f2bf(vv.x); o.y = f2bf(vv.y); o.z = f2bf(vv.z); o.w = f2bf(vv.w);
                }
                *(us4*)(kvw + row * 64 + ((chunk ^ (row & 7)) << 3) + tin) = o;
            }
        }
        __syncthreads();

        // --- ctx MFMA: ctx[c][d] += ek^T . v over this tile's 64 tokens ---
#pragma unroll
        for (int kt = 0; kt < 2; ++kt) {
            short8 af[3], bf2[3];
#pragma unroll
            for (int i = 0; i < 3; ++i) {
                const int ra = i * 16 + c16;
                af[i]  = *(const short8*)(kvw + ra * 64 + (((kt * 4 + q) ^ (ra & 7)) << 3));
                const int rb = 48 + i * 16 + c16;
                bf2[i] = *(const short8*)(kvw + rb * 64 + (((kt * 4 + q) ^ (rb & 7)) << 3));
            }
#pragma unroll
            for (int ct = 0; ct < 3; ++ct)
#pragma unroll
                for (int dt = 0; dt < 3; ++dt)
                    ctxacc[ct][dt] = MFMA(af[ct], bf2[dt], ctxacc[ct][dt]);
        }
    }

    // --- finalize: Z and ctx atomics ---
#pragma unroll
    for (int j = 0; j < 3; ++j) {
        float v = zp[j];
        v += __shfl_xor(v, 16);
        v += __shfl_xor(v, 32);
        if (l < 16) atomicAdd(&Z[(b * 8 + w) * 48 + j * 16 + c16], v);
    }
#pragma unroll
    for (int ct = 0; ct < 3; ++ct)
#pragma unroll
        for (int dt = 0; dt < 3; ++dt)
#pragma unroll
            for (int r = 0; r < 4; ++r) {
                const int c = ct * 16 + q * 4 + r;
                const int d = dt * 16 + c16;
                atomicAdd(&ctx[((size_t)(b * 8 + w) * 48 + c) * 48 + d], ctxacc[ct][dt][r]);
            }
}

// ---------------------------------------------------------------------------
// kB: ctxT[bh][d][c(pad 64)] = bf16( ctx[bh][c][d] / Z[bh][c] ), pad zeros.
// ---------------------------------------------------------------------------
__global__ void kB(const float* __restrict__ ctx, const float* __restrict__ Z,
                   unsigned short* __restrict__ ctxT)
{
    const int e = blockIdx.x * 256 + threadIdx.x;    // < 196608
    const int bh = e / 3072;
    const int r = e % 3072;
    const int d = r >> 6;
    const int c = r & 63;
    float v = 0.f;
    if (c < 48) v = ctx[((size_t)bh * 48 + c) * 48 + d] / Z[bh * 48 + c];
    ctxT[e] = f2bf(v);
}

// ---------------------------------------------------------------------------
// kC: per 32-token block (256 thr = 4 waves, wave = 2 heads):
// q-GEMM (MFMA) -> in-register softmax (shfl) -> y = q̂@ctx (MFMA) -> proj (MFMA)+bias.
// grid = 4096.
// ---------------------------------------------------------------------------
__global__ __launch_bounds__(256, 2) void kC(const float* __restrict__ x,
        const unsigned short* __restrict__ WqkvT,
        const unsigned short* __restrict__ ctxT,
        const unsigned short* __restrict__ WpT,
        const float* __restrict__ bp, float* __restrict__ out)
{
    __shared__ __align__(16) unsigned short xs[32 * 392];   // x tile; reused as y tile
    __shared__ __align__(16) unsigned short qs[32 * 520];   // q̂ in A-layout [t][h*64+c]

    const int tid = threadIdx.x;
    const int w   = tid >> 6;
    const int l   = tid & 63;
    const int q   = l >> 4;
    const int c16 = l & 15;
    const int blk = blockIdx.x;
    const size_t tok0 = (size_t)blk * 32;
    const int b = blk >> 9;

    {   // stage x
        const int st = tid >> 3, sq = tid & 7;
        const float* xg = x + (tok0 + st) * 384 + sq * 4;
        unsigned short* xw = xs + st * 392 + sq * 4;
#pragma unroll
        for (int i = 0; i < 12; ++i) {
            float4 v = *(const float4*)(xg + i * 32);
            us4 o; o.x = f2bf(v.x); o.y = f2bf(v.y); o.z = f2bf(v.z); o.w = f2bf(v.w);
            *(us4*)(xw + i * 32) = o;
        }
    }
    __syncthreads();

    // --- q-GEMM: 32 tok x 96 cols per wave (heads 2w, 2w+1), K=384 ---
    f32x4 acc[2][6];
#pragma unroll
    for (int mt = 0; mt < 2; ++mt)
#pragma unroll
        for (int j = 0; j < 6; ++j) acc[mt][j] = (f32x4){0.f, 0.f, 0.f, 0.f};

#pragma unroll
    for (int ks = 0; ks < 12; ++ks) {
        short8 a0 = *(const short8*)(xs + (c16) * 392 + ks * 32 + q * 8);
        short8 a1 = *(const short8*)(xs + (16 + c16) * 392 + ks * 32 + q * 8);
#pragma unroll
        for (int j = 0; j < 6; ++j) {
            const int nt = w * 6 + j;
            short8 bf = *(const short8*)(WqkvT + (size_t)(nt * 16 + c16) * 384 + ks * 32 + q * 8);
            acc[0][j] = MFMA(a0, bf, acc[0][j]);
            acc[1][j] = MFMA(a1, bf, acc[1][j]);
        }
    }
    __syncthreads();    // xs free for reuse as ys

    // --- softmax over C=48 per (token, head), fully in registers + shfl ---
#pragma unroll
    for (int hh = 0; hh < 2; ++hh) {
        const int h = 2 * w + hh;
        f32x4 e[2][3];
#pragma unroll
        for (int mt = 0; mt < 2; ++mt)
#pragma unroll
            for (int jj = 0; jj < 3; ++jj) {
                f32x4 vv = acc[mt][hh * 3 + jj];
                e[mt][jj].x = __expf(vv.x); e[mt][jj].y = __expf(vv.y);
                e[mt][jj].z = __expf(vv.z); e[mt][jj].w = __expf(vv.w);
            }
#pragma unroll
        for (int mt = 0; mt < 2; ++mt)
#pragma unroll
            for (int r = 0; r < 4; ++r) {
                float s = e[mt][0][r] + e[mt][1][r] + e[mt][2][r];
                s += __shfl_xor(s, 1); s += __shfl_xor(s, 2);
                s += __shfl_xor(s, 4); s += __shfl_xor(s, 8);
                const float inv = 1.0f / s;
                e[mt][0][r] *= inv; e[mt][1][r] *= inv; e[mt][2][r] *= inv;
            }
        // write q̂ (A-layout, column writes)
#pragma unroll
        for (int mt = 0; mt < 2; ++mt)
#pragma unroll
            for (int jj = 0; jj < 3; ++jj) {
                const int c = jj * 16 + c16;
#pragma unroll
                for (int r = 0; r < 4; ++r) {
                    const int t = mt * 16 + q * 4 + r;
                    qs[t * 520 + h * 64 + c] = f2bf(e[mt][jj][r]);
                }
            }
    }
    {   // zero the K-pad region c in [48,64) for this wave's heads
        const int t = l & 31, hp = l >> 5;
        const int h = 2 * w + hp;
        us8 z8 = {0, 0, 0, 0, 0, 0, 0, 0};
        *(us8*)(qs + t * 520 + h * 64 + 48) = z8;
    }
    __syncthreads();

    // --- y = q̂ @ ctx̂ per head (K=64 padded), write y bf16 into xs as [t][384] ---
#pragma unroll
    for (int hh = 0; hh < 2; ++hh) {
        const int h = 2 * w + hh;
        f32x4 y[2][3];
#pragma unroll
        for (int mt = 0; mt < 2; ++mt)
#pragma unroll
            for (int dt = 0; dt < 3; ++dt) y[mt][dt] = (f32x4){0.f, 0.f, 0.f, 0.f};
#pragma unroll
        for (int ks = 0; ks < 2; ++ks) {
            short8 a0 = *(const short8*)(qs + (c16) * 520 + h * 64 + ks * 32 + q * 8);
            short8 a1 = *(const short8*)(qs + (16 + c16) * 520 + h * 64 + ks * 32 + q * 8);
#pragma unroll
            for (int dt = 0; dt < 3; ++dt) {
                short8 bf = *(const short8*)(ctxT + ((size_t)(b * 8 + h) * 48 + dt * 16 + c16) * 64 + ks * 32 + q * 8);
                y[0][dt] = MFMA(a0, bf, y[0][dt]);
                y[1][dt] = MFMA(a1, bf, y[1][dt]);
            }
        }
#pragma unroll
        for (int mt = 0; mt < 2; ++mt)
#pragma unroll
            for (int dt = 0; dt < 3; ++dt) {
                const int dcol = h * 48 + dt * 16 + c16;
#pragma unroll
                for (int r = 0; r < 4; ++r) {
                    const int t = mt * 16 + q * 4 + r;
                    xs[t * 392 + dcol] = f2bf(y[mt][dt][r]);
                }
            }
    }
    __syncthreads();

    // --- proj: out = y @ Wp + b, 32 tok x 96 cols per wave, K=384 ---
    f32x4 po[2][6];
#pragma unroll
    for (int mt = 0; mt < 2; ++mt)
#pragma unroll
        for (int j = 0; j < 6; ++j) po[mt][j] = (f32x4){0.f, 0.f, 0.f, 0.f};

#pragma unroll
    for (int ks = 0; ks < 12; ++ks) {
        short8 a0 = *(const short8*)(xs + (c16) * 392 + ks * 32 + q * 8);
        short8 a1 = *(const short8*)(xs + (16 + c16) * 392 + ks * 32 + q * 8);
#pragma unroll
        for (int j = 0; j < 6; ++j) {
            const int nt = w * 6 + j;
            short8 bf = *(const short8*)(WpT + (size_t)(nt * 16 + c16) * 384 + ks * 32 + q * 8);
            po[0][j] = MFMA(a0, bf, po[0][j]);
            po[1][j] = MFMA(a1, bf, po[1][j]);
        }
    }

    // --- epilogue: bias + store ---
#pragma unroll
    for (int j = 0; j < 6; ++j) {
        const int col = (w * 6 + j) * 16 + c16;
        const float bv = bp[col];
#pragma unroll
        for (int mt = 0; mt < 2; ++mt)
#pragma unroll
            for (int r = 0; r < 4; ++r) {
                const int t = mt * 16 + q * 4 + r;
                out[(tok0 + t) * 384 + col] = po[mt][j][r] + bv;
            }
    }
}

// ---------------------------------------------------------------------------
extern "C" void kernel_launch(void* const* d_in, const int* in_sizes, int n_in,
                              void* d_out, int out_size, void* d_ws, size_t ws_size,
                              hipStream_t stream)
{
    (void)in_sizes; (void)n_in; (void)out_size; (void)ws_size;
    const float* x    = (const float*)d_in[0];
    const float* Wqkv = (const float*)d_in[1];
    const float* Wp   = (const float*)d_in[2];
    const float* bp   = (const float*)d_in[3];
    float* out = (float*)d_out;

    char* p = (char*)d_ws;
    float* ctx = (float*)p;                 p += CTX_ELEMS * 4;     // 589824 B
    float* Z   = (float*)p;                 p += Z_ELEMS * 4;       // 12288 B
    unsigned short* WqkvT = (unsigned short*)p;  p += TD_ * D_ * 2;      // 884736 B
    unsigned short* WpT   = (unsigned short*)p;  p += D_ * D_ * 2;       // 294912 B
    unsigned short* ctxT  = (unsigned short*)p;                          // 393216 B

    hipMemsetAsync(d_ws, 0, (CTX_ELEMS + Z_ELEMS) * sizeof(float), stream);
    kP<<<dim3(576), dim3(256), 0, stream>>>(Wqkv, Wp, WqkvT, WpT);
    kA<<<dim3(256), dim3(512), 0, stream>>>(x, WqkvT, ctx, Z);
    kB<<<dim3(768), dim3(256), 0, stream>>>(ctx, Z, ctxT);
    kC<<<dim3(4096), dim3(256), 0, stream>>>(x, WqkvT, ctxT, WpT, bp, out);
}